// Round 3
// baseline (218.894 us; speedup 1.0000x reference)
//
#include <hip/hip_runtime.h>
#include <hip/hip_cooperative_groups.h>

namespace cg = cooperative_groups;

// Pipeline_8400956031319: dual greedy NMS (8192 det + 8192 rpn, IOU>0.6,
// index order) + argmax masking.
//
// R14 rev — ONE cooperative dispatch. R13's binning made every kernel tiny
// (all top-5 rocprof rows = the 40us harness ws-poison fill) but total
// 79.5 > R11's 75.5: 4 dispatches x ~5-7us graph-node gap ate the win.
// Non-fill budget was 39.5us for ~12us of work. Fix: fuse zero+bin+pair+
// solve into one hipLaunchCooperativeKernel with 3 grid.sync()s.
// Unlike the old failed coop attempt: no 512x redundant solve (only 32
// blocks solve after the final sync) and no full scan (binning).
// Residency: LDS = union(pair 36K, solve 56K) = 56.5K -> 2 blocks/CU;
// __launch_bounds__(512,4) caps VGPR at 128; 512 blocks = 2x256 CUs.
//
//   Phase Z: block 0 zeroes binCnt[512]+ovf.            grid.sync
//   Phase B: 16384 rows binned; cell = identical clamp formula; scatter
//            {box float4, row id} via global atomicAdd.  grid.sync
//   Phase P: one block per (set,cell): gather 3x3 neighborhood (~288,
//            per-cell contiguous float4 runs) into LDS, center first;
//            flattened pair loop, exact ref IOU; emit edges (i<<13|j)
//            once via orig_a < orig_b. Overflow -> exact full-scan
//            fallback (never taken).                     grid.sync
//   Phase S: blocks 0..31 (set,slice): LDS edge cache, Jacobi fixpoint
//            keep[j] = !(exists i<j edge with keep[i]) (unique fixpoint
//            == greedy NMS), coalesced float4 epilogue slice. Blocks
//            >=32 exit after the last sync.

constexpr int NROWS = 8192;
constexpr int NKW   = 256;      // keep words (u32) per set
constexpr unsigned ACAP = 512;  // bin capacity per (set,cell) (mean ~32)
constexpr unsigned BCAP = 1536; // staged 3x3 neighborhood cap (mean ~288)
constexpr unsigned RCAP = 2048; // per-block edge region cap (mean ~12)
constexpr unsigned ELDS = 12288;// solve LDS edge cache (~4x expected ~3k)
#define IOU_T 0.6f

// ws layout:
//   [0      ) edge cnts  [512] u32   (written unconditionally by phase P)
//   [2048   ) bin  cnts  [512] u32   (zeroed by phase Z)
//   [4096   ) ovf flag   u32         (zeroed by phase Z)
//   [8192   ) edges      [512][RCAP] u32    (4 MB)
//   [+4MB   ) binBox     [512][ACAP] float4 (4 MB, 16B-aligned)
//   [+4MB   ) binId      [512][ACAP] u32    (1 MB)
constexpr size_t OFF_ECNT  = 0;
constexpr size_t OFF_BCNT  = 2048;
constexpr size_t OFF_OVF   = 4096;
constexpr size_t OFF_EDGES = 8192;
constexpr size_t OFF_BBOX  = OFF_EDGES + (size_t)512 * RCAP * 4;
constexpr size_t OFF_BID   = OFF_BBOX  + (size_t)512 * ACAP * 16;

union __align__(16) Smem {
  struct {                       // phase P: 36.9 KB
    float4   B4[BCAP];
    float    Bar[BCAP];
    unsigned Bid[BCAP];
  } p;
  struct {                       // phase S: 56.5 KB
    unsigned eL[ELDS];
    unsigned rcnt[256], roff[256];
    unsigned kbuf[2][NKW];
    float    vmsk[512], imsk[512];
  } s;
};

__global__ __launch_bounds__(512, 4) void fused_kernel(
    const float* __restrict__ det, const float* __restrict__ rpn,
    unsigned* __restrict__ ecnt, unsigned* __restrict__ binCnt,
    unsigned* __restrict__ ovf,  unsigned* __restrict__ edges,
    float4* __restrict__ binBox, unsigned* __restrict__ binId,
    float* __restrict__ out)
{
  cg::grid_group grid = cg::this_grid();
  __shared__ Smem U;
  __shared__ unsigned ncell[9], ncnt9[9], noff9[9];
  __shared__ unsigned nN_sh, na_sh, nb_sh, eC, bad;
  __shared__ unsigned Etot_sh;
  __shared__ int changed[2];

  const int bid = blockIdx.x;
  const int t   = threadIdx.x;

  // ---- Phase Z: zero bin counters + ovf (block 0 only) --------------------
  if (bid == 0) { binCnt[t] = 0u; if (t == 0) *ovf = 0u; }
  grid.sync();

  // ---- Phase B: bin all 16384 rows ----------------------------------------
  {
    const int gtid = (bid << 9) + t;
    if (gtid < 2 * NROWS) {
      const int bset = gtid >> 13;
      const int r    = gtid & (NROWS - 1);
      const float* src  = (bset == 0) ? det : rpn;
      const int    strd = (bset == 0) ? 9 : 6;
      const float* p = src + (size_t)r * strd + 1;
      const float x1 = p[0], y1 = p[1], x2 = p[2], y2 = p[3];
      const float cxe = 0.5f * (x1 + x2), cye = 0.5f * (y1 + y2);
      const int ccx = min(15, max(0, (int)(cxe * (1.0f / 128.0f))));
      const int ccy = min(15, max(0, (int)(cye * (1.0f / 128.0f))));
      const unsigned cell = (unsigned)(bset * 256 + ccy * 16 + ccx);
      const unsigned slot = atomicAdd(&binCnt[cell], 1u);
      if (slot < ACAP) {
        binBox[(size_t)cell * ACAP + slot] = make_float4(x1, y1, x2, y2);
        binId [(size_t)cell * ACAP + slot] = (unsigned)r;
      } else {
        atomicOr(ovf, 1u);
      }
    }
  }
  grid.sync();

  // ---- Phase P: pair tests, one block per (set,cell) ----------------------
  {
    const int set = bid >> 8;
    const int cellid = bid & 255;
    const int cx = cellid & 15, cy = cellid >> 4;
    unsigned* myedges = edges + ((size_t)(set * 256 + cellid)) * RCAP;

    if (t == 0) {
      unsigned nN = 0;
      ncell[nN++] = (unsigned)(set * 256 + cellid);   // CENTER FIRST
      for (int dy = -1; dy <= 1; ++dy)
        for (int dx = -1; dx <= 1; ++dx) {
          if (dx == 0 && dy == 0) continue;
          const int nx = cx + dx, ny = cy + dy;
          if (nx >= 0 && nx < 16 && ny >= 0 && ny < 16)
            ncell[nN++] = (unsigned)(set * 256 + ny * 16 + nx);
        }
      nN_sh = nN; eC = 0u; bad = *ovf;
    }
    __syncthreads();
    const unsigned nN = nN_sh;
    if (t < (int)nN) ncnt9[t] = min(binCnt[ncell[t]], ACAP);
    __syncthreads();
    if (t == 0) {
      unsigned off = 0;
      for (unsigned n = 0; n < nN; ++n) { noff9[n] = off; off += ncnt9[n]; }
      na_sh = ncnt9[0]; nb_sh = off;
      if (off > BCAP) bad = 1u;
    }
    __syncthreads();

    const unsigned na = na_sh, nb = nb_sh;
    const bool ok = (bad == 0u);            // block-uniform

    if (ok) {
      // gather neighborhood: per-cell contiguous float4 runs => coalesced
      for (unsigned idx = t; idx < nb; idx += 512) {
        unsigned n = 0;
        while (idx >= noff9[n] + ncnt9[n]) ++n;        // <=9 iterations
        const unsigned k = idx - noff9[n];
        const size_t  g = (size_t)ncell[n] * ACAP + k;
        const float4 bx = binBox[g];
        U.p.B4[idx]  = bx;
        U.p.Bar[idx] = fmaxf(bx.z - bx.x, 0.0f) * fmaxf(bx.w - bx.y, 0.0f);
        U.p.Bid[idx] = binId[g];
      }
    }
    __syncthreads();

    if (ok) {
      // flattened pair phase: a = center entries [0,na), b = all [0,nb)
      const unsigned tot = na * nb;
      for (unsigned pi = t; pi < tot; pi += 512) {
        const unsigned ai = pi / nb, x = pi - ai * nb;
        const unsigned ia = U.p.Bid[ai], ib = U.p.Bid[x];
        if (ia < ib) {                               // emit-once; skips self
          const float4 A = U.p.B4[ai], B = U.p.B4[x];
          const float ix1 = fmaxf(A.x, B.x), iy1 = fmaxf(A.y, B.y);
          const float ix2 = fminf(A.z, B.z), iy2 = fminf(A.w, B.w);
          const float inter = fmaxf(ix2 - ix1, 0.0f) * fmaxf(iy2 - iy1, 0.0f);
          if (inter > 0.0f) {
            const float uni = U.p.Bar[ai] + U.p.Bar[x] - inter;  // ref order
            const float iou = inter / fmaxf(uni, 1e-9f);         // ref expr
            if (iou > IOU_T) {
              const unsigned slot = atomicAdd(&eC, 1u);          // LDS atomic
              if (slot < RCAP) myedges[slot] = (ia << 13) | ib;
            }
          }
        }
      }
    } else {
      // exact fallback (never taken for this data): a = rows in this cell,
      // b = ALL rows; out-of-neighborhood pairs have inter==0 geometrically,
      // so semantics are identical to the fast path.
      const float* src  = (set == 0) ? det : rpn;
      const int    strd = (set == 0) ? 9 : 6;
      for (int ra = 0; ra < NROWS; ++ra) {
        const float* pa = src + (size_t)ra * strd + 1;
        const float ax1 = pa[0], ay1 = pa[1], ax2 = pa[2], ay2 = pa[3];
        const float cxe = 0.5f * (ax1 + ax2), cye = 0.5f * (ay1 + ay2);
        const int ccx = min(15, max(0, (int)(cxe * (1.0f / 128.0f))));
        const int ccy = min(15, max(0, (int)(cye * (1.0f / 128.0f))));
        if (ccx != cx || ccy != cy) continue;        // uniform skip
        const float aar = fmaxf(ax2 - ax1, 0.0f) * fmaxf(ay2 - ay1, 0.0f);
        for (int rb = t; rb < NROWS; rb += 512) {
          if ((unsigned)ra >= (unsigned)rb) continue;
          const float* pb = src + (size_t)rb * strd + 1;
          const float bx1 = pb[0], by1 = pb[1], bx2 = pb[2], by2 = pb[3];
          const float ix1 = fmaxf(ax1, bx1), iy1 = fmaxf(ay1, by1);
          const float ix2 = fminf(ax2, bx2), iy2 = fminf(ay2, by2);
          const float inter = fmaxf(ix2 - ix1, 0.0f) * fmaxf(iy2 - iy1, 0.0f);
          if (inter > 0.0f) {
            const float bar = fmaxf(bx2 - bx1, 0.0f) * fmaxf(by2 - by1, 0.0f);
            const float uni = aar + bar - inter;
            const float iou = inter / fmaxf(uni, 1e-9f);
            if (iou > IOU_T) {
              const unsigned slot = atomicAdd(&eC, 1u);
              if (slot < RCAP) myedges[slot] = ((unsigned)ra << 13) | (unsigned)rb;
            }
          }
        }
      }
    }
    __syncthreads();
    if (t == 0) ecnt[set * 256 + cellid] = min(eC, RCAP);
  }
  grid.sync();

  // ---- Phase S: fixpoint + epilogue, blocks 0..31 only --------------------
  if (bid >= 32) return;

  const int set = bid >> 4;
  const int slice = bid & 15;
  const unsigned* gedges = edges + (size_t)set * 256 * RCAP;

  if (t < 256) U.s.rcnt[t] = min(ecnt[set * 256 + t], RCAP);
  __syncthreads();

  // wave0 shuffle-scan of 256 region counts (4/lane)
  if (t < 64) {
    const unsigned h0 = U.s.rcnt[4 * t], h1 = U.s.rcnt[4 * t + 1];
    const unsigned h2 = U.s.rcnt[4 * t + 2], h3 = U.s.rcnt[4 * t + 3];
    const unsigned lsum = h0 + h1 + h2 + h3;
    unsigned incl = lsum;
    #pragma unroll
    for (int d = 1; d < 64; d <<= 1) {
      const unsigned v = __shfl_up(incl, d);
      if (t >= d) incl += v;
    }
    const unsigned base = incl - lsum;
    U.s.roff[4 * t] = base;                     U.s.roff[4 * t + 1] = base + h0;
    U.s.roff[4 * t + 2] = base + h0 + h1;       U.s.roff[4 * t + 3] = base + h0 + h1 + h2;
    if (t == 63) Etot_sh = incl;
  }
  if (t < NKW) U.s.kbuf[0][t] = 0xFFFFFFFFu;
  __syncthreads();

  const unsigned Etot = Etot_sh;
  const bool cached = (Etot <= ELDS);
  if (cached) {                 // gather: 2 threads per region (~6 loads ea)
    const unsigned rg = (unsigned)t >> 1, ln = (unsigned)t & 1u;
    const unsigned c = U.s.rcnt[rg], o = U.s.roff[rg];
    for (unsigned k = ln; k < c; k += 2u)
      U.s.eL[o + k] = gedges[(size_t)rg * RCAP + k];
  }
  __syncthreads();

  int cur = 0;
  for (int round = 0; round < NROWS + 8; ++round) {
    const int nxt = cur ^ 1;
    if (t == 0) changed[round & 1] = 0;
    if (t < NKW) U.s.kbuf[nxt][t] = 0xFFFFFFFFu;
    __syncthreads();

    if (cached) {
      for (unsigned e = t; e < Etot; e += 512) {
        const unsigned pk = U.s.eL[e];
        const unsigned i = pk >> 13, j = pk & 8191u;
        if ((U.s.kbuf[cur][i >> 5] >> (i & 31)) & 1u)
          atomicAnd(&U.s.kbuf[nxt][j >> 5], ~(1u << (j & 31)));
      }
    } else {                    // exact slow path (never taken)
      for (unsigned r = (unsigned)t >> 1; r < 256u; r += 256u) {
        const unsigned c = U.s.rcnt[r];
        for (unsigned k = (unsigned)t & 1u; k < c; k += 2u) {
          const unsigned pk = gedges[(size_t)r * RCAP + k];
          const unsigned i = pk >> 13, j = pk & 8191u;
          if ((U.s.kbuf[cur][i >> 5] >> (i & 31)) & 1u)
            atomicAnd(&U.s.kbuf[nxt][j >> 5], ~(1u << (j & 31)));
        }
      }
    }
    __syncthreads();

    if (t < NKW && U.s.kbuf[nxt][t] != U.s.kbuf[cur][t]) changed[round & 1] = 1;
    __syncthreads();

    cur = nxt;
    if (!changed[round & 1]) break;  // F(x)==x -> the unique fixpoint
  }

  // epilogue slice: 512 rows per block, coalesced.
  // phase 1: per-row mask (0.0/1.0) into LDS; phase 2: stream contiguous
  // float4 with exact magic-div row decode (col stride 9 => d/9, 6 => d/6).
  const int r0 = slice * 512;
  if (set == 0) {
    {
      const int i = r0 + t;
      const bool kd = (U.s.kbuf[cur][i >> 5] >> (i & 31)) & 1u;
      const float* p = det + (size_t)i * 9;
      const float sc0 = p[5], sc1 = p[6], sc2 = p[7], sc3 = p[8];
      int am = 0; float best = sc0;
      if (sc1 > best) { best = sc1; am = 1; }   // first-max, like jnp.argmax
      if (sc2 > best) { best = sc2; am = 2; }
      if (sc3 > best) { best = sc3; am = 3; }
      U.s.vmsk[t] = (kd && am != 0) ? 1.0f : 0.0f;
      U.s.imsk[t] = (kd && am == 0) ? 1.0f : 0.0f;
    }
    __syncthreads();
    // slice = 512 rows x 9 dw = 4608 dw = 1152 float4, 16B-aligned bases
    const float4* in4 = reinterpret_cast<const float4*>(det + (size_t)r0 * 9);
    float4* o0 = reinterpret_cast<float4*>(out + (size_t)r0 * 9);
    float4* o1 = reinterpret_cast<float4*>(out + (size_t)NROWS * 9 + (size_t)r0 * 9);
    for (int q = t; q < 1152; q += 512) {
      const float4 v = in4[q];
      const float* vp = reinterpret_cast<const float*>(&v);
      float4 a, b;
      float* ap = reinterpret_cast<float*>(&a);
      float* bp = reinterpret_cast<float*>(&b);
      #pragma unroll
      for (int j = 0; j < 4; ++j) {
        const unsigned d = (unsigned)(q * 4 + j);
        const unsigned row = (d * 7282u) >> 16;        // == d/9 for d<4608
        ap[j] = vp[j] * U.s.vmsk[row];
        bp[j] = vp[j] * U.s.imsk[row];
      }
      o0[q] = a; o1[q] = b;
    }
  } else {
    {
      const int i = r0 + t;
      const bool kr = (U.s.kbuf[cur][i >> 5] >> (i & 31)) & 1u;
      U.s.vmsk[t] = kr ? 1.0f : 0.0f;
    }
    __syncthreads();
    // slice = 512 rows x 6 dw = 3072 dw = 768 float4, 16B-aligned bases
    const float4* in4 = reinterpret_cast<const float4*>(rpn + (size_t)r0 * 6);
    float4* o2 = reinterpret_cast<float4*>(out + (size_t)NROWS * 18 + (size_t)r0 * 6);
    for (int q = t; q < 768; q += 512) {
      const float4 v = in4[q];
      const float* vp = reinterpret_cast<const float*>(&v);
      float4 a;
      float* ap = reinterpret_cast<float*>(&a);
      #pragma unroll
      for (int j = 0; j < 4; ++j) {
        const unsigned d = (unsigned)(q * 4 + j);
        const unsigned row = (d * 10923u) >> 16;       // == d/6 for d<3072
        ap[j] = vp[j] * U.s.vmsk[row];
      }
      o2[q] = a;
    }
  }
}

// ---------------------------------------------------------------------------
extern "C" void kernel_launch(void* const* d_in, const int* in_sizes, int n_in,
                              void* d_out, int out_size, void* d_ws, size_t ws_size,
                              hipStream_t stream)
{
  const float* det = (const float*)d_in[0];   // 8192 x 9 fp32
  const float* rpn = (const float*)d_in[1];   // 8192 x 6 fp32
  float* out = (float*)d_out;                 // 8192*9 + 8192*9 + 8192*6 fp32

  char* ws = (char*)d_ws;
  unsigned* ecnt   = (unsigned*)(ws + OFF_ECNT);
  unsigned* binCnt = (unsigned*)(ws + OFF_BCNT);
  unsigned* ovf    = (unsigned*)(ws + OFF_OVF);
  unsigned* edges  = (unsigned*)(ws + OFF_EDGES);
  float4*   binBox = (float4*)  (ws + OFF_BBOX);
  unsigned* binId  = (unsigned*)(ws + OFF_BID);

  void* args[] = { (void*)&det, (void*)&rpn, (void*)&ecnt, (void*)&binCnt,
                   (void*)&ovf, (void*)&edges, (void*)&binBox, (void*)&binId,
                   (void*)&out };
  hipLaunchCooperativeKernel((const void*)fused_kernel, dim3(512), dim3(512),
                             args, 0, stream);
}

// Round 4
// 78.249 us; speedup vs baseline: 2.7974x; 2.7974x over previous
//
#include <hip/hip_runtime.h>

// Pipeline_8400956031319: dual greedy NMS (8192 det + 8192 rpn, IOU>0.6,
// index order) + argmax masking.
//
// R15 rev — TWO dispatches, no grid.sync. R14's cooperative fusion was a
// disaster: 3x cg::grid.sync() = ~45us EACH on gfx950 (device-scope sync
// must wb/inv the 8 non-coherent per-XCD L2s; cg's protocol on top) =>
// fused_kernel 154us. A dispatch boundary does the same flush in ~5us.
// Gap model (R11: 2 disp, ovh ~8us; R13: 5 nodes, ovh ~26us): ~5-6us per
// boundary => minimize dispatch count without any full grid barrier.
//
//   K1 bin_part (32 blocks x 512): per-block PRIVATE bins — LDS count +
//      prefix, write compacted {box,id} entries + packed {off,cnt}[256]
//      tables, plain stores only. No global atomics, no memset dispatch
//      (also zeroes the 4B ticket word). Per-(block,cell) count <= 512
//      => partials can never overflow.
//   K2 pairsolve (512 blocks x 512): block (set,cell) gathers its 3x3
//      neighborhood from 16 partials (<=144 runs; LDS prefix + binary
//      search), center cell first; identical flattened pair loop + exact
//      ref IOU; edges (i<<13|j, once via orig_a < orig_b) written with
//      AGENT-scope atomics (LLC-coherent across XCDs). Then the ticket
//      trick replaces the pair->solve dispatch: every block RELEASE-adds
//      a ticket; the last 32 tickets become solver blocks, spin (RELAXED
//      + s_sleep) until all 512 arrived, ACQUIRE, then run the unchanged
//      Jacobi fixpoint (keep[j] = !(exists i<j edge with keep[i]); unique
//      fixpoint == greedy NMS) + coalesced float4 epilogue. Deadlock-safe
//      without cooperative launch: spinners are the 32 LAST arrivals of
//      512 blocks => unscheduled blocks always find free slots.

constexpr int NROWS = 8192;
constexpr int NKW   = 256;      // keep words (u32) per set
constexpr unsigned BCAP = 1536; // staged 3x3 neighborhood cap (mean ~288)
constexpr unsigned RCAP = 2048; // per-cell edge region cap (mean ~12)
constexpr unsigned ELDS = 12288;// solve LDS edge cache (~4x expected ~3k)
#define IOU_T 0.6f

// ws layout:
//   [0    ) ecnt    [512] u32            (agent-atomic, written by all cells)
//   [2048 ) ticket  u32                  (zeroed by K1)
//   [4096 ) edges   [512][RCAP] u32      (4 MB, agent-atomic)
//   [+4MB ) partBox [32*512] float4      (256 KB, plain — cross-dispatch)
//   [+    ) partId  [32*512] u32         (64 KB)
//   [+    ) partOfs [32][256] u32        (32 KB, packed off | cnt<<16)
constexpr size_t OFF_ECNT  = 0;
constexpr size_t OFF_TICK  = 2048;
constexpr size_t OFF_EDGES = 4096;
constexpr size_t OFF_PBOX  = OFF_EDGES + (size_t)512 * RCAP * 4;
constexpr size_t OFF_PID   = OFF_PBOX  + (size_t)32 * 512 * 16;
constexpr size_t OFF_POFS  = OFF_PID   + (size_t)32 * 512 * 4;

__device__ __forceinline__ unsigned aload(unsigned* p) {
  return __hip_atomic_load(p, __ATOMIC_RELAXED, __HIP_MEMORY_SCOPE_AGENT);
}
__device__ __forceinline__ void astore(unsigned* p, unsigned v) {
  __hip_atomic_store(p, v, __ATOMIC_RELAXED, __HIP_MEMORY_SCOPE_AGENT);
}

// ---------------------------------------------------------------------------
// K1: partial binning. 32 blocks x 512 threads; block b: set=b>>4, rows
// [(b&15)*512, +512). All plain stores — next dispatch boundary flushes.
// ---------------------------------------------------------------------------
__global__ __launch_bounds__(512) void bin_part_kernel(
    const float* __restrict__ det, const float* __restrict__ rpn,
    float4* __restrict__ partBox, unsigned* __restrict__ partId,
    unsigned* __restrict__ partOfs, unsigned* __restrict__ ticket)
{
  const int b = blockIdx.x;
  const int set = b >> 4;
  const int t = threadIdx.x;
  if (b == 0 && t == 0) *ticket = 0u;     // flushed at dispatch boundary

  const float* src  = (set == 0) ? det : rpn;
  const int    strd = (set == 0) ? 9 : 6;
  const int r = ((b & 15) << 9) + t;

  __shared__ unsigned cnt[256], off[256];
  if (t < 256) cnt[t] = 0u;
  __syncthreads();

  const float* p = src + (size_t)r * strd + 1;
  const float x1 = p[0], y1 = p[1], x2 = p[2], y2 = p[3];
  const float cxe = 0.5f * (x1 + x2), cye = 0.5f * (y1 + y2);
  const int ccx = min(15, max(0, (int)(cxe * (1.0f / 128.0f))));
  const int ccy = min(15, max(0, (int)(cye * (1.0f / 128.0f))));
  const unsigned cell = (unsigned)(ccy * 16 + ccx);          // local 0..255
  const unsigned rank = atomicAdd(&cnt[cell], 1u);           // LDS atomic
  __syncthreads();

  // wave0 shuffle-scan of 256 counts (4/lane) -> exclusive off[]
  if (t < 64) {
    const unsigned h0 = cnt[4 * t], h1 = cnt[4 * t + 1];
    const unsigned h2 = cnt[4 * t + 2], h3 = cnt[4 * t + 3];
    const unsigned lsum = h0 + h1 + h2 + h3;
    unsigned incl = lsum;
    #pragma unroll
    for (int d = 1; d < 64; d <<= 1) {
      const unsigned v = __shfl_up(incl, d);
      if (t >= d) incl += v;
    }
    const unsigned base = incl - lsum;
    off[4 * t] = base;               off[4 * t + 1] = base + h0;
    off[4 * t + 2] = base + h0 + h1; off[4 * t + 3] = base + h0 + h1 + h2;
  }
  __syncthreads();

  const unsigned pos = ((unsigned)b << 9) + off[cell] + rank;
  partBox[pos] = make_float4(x1, y1, x2, y2);
  partId [pos] = (unsigned)r;
  if (t < 256) partOfs[b * 256 + t] = off[t] | (cnt[t] << 16);
}

// ---------------------------------------------------------------------------
// K2: pair + ticket + solve + epilogue. 512 blocks x 512 threads.
// ---------------------------------------------------------------------------
union __align__(16) Smem {
  struct {                       // pair phase: ~38.2 KB
    float4   B4[BCAP];
    float    Bar[BCAP];
    unsigned Bid[BCAP];
    unsigned runStart[144];      // exclusive prefix of run counts
    unsigned runBase[144];       // absolute entry index of run start
  } p;
  struct {                       // solve phase: ~57.3 KB
    unsigned eL[ELDS];
    unsigned rcnt[256], roff[256];
    unsigned kbuf[2][NKW];
    float    vmsk[512], imsk[512];
  } s;
};

__global__ __launch_bounds__(512, 4) void pairsolve_kernel(
    const float* __restrict__ det, const float* __restrict__ rpn,
    const float4* __restrict__ partBox, const unsigned* __restrict__ partId,
    const unsigned* __restrict__ partOfs, unsigned* __restrict__ ecnt,
    unsigned* __restrict__ edges, unsigned* __restrict__ ticket,
    float* __restrict__ out)
{
  __shared__ Smem U;
  __shared__ unsigned ncell[9];
  __shared__ unsigned nN_sh, nR_sh, na_sh, nb_sh, eC, bad, tk_sh, Etot_sh;
  __shared__ int changed[2];

  const int bid = blockIdx.x;
  const int t   = threadIdx.x;

  // ---- pair phase: one block per (set,cell) -------------------------------
  {
    const int set = bid >> 8;
    const int cellid = bid & 255;
    const int cx = cellid & 15, cy = cellid >> 4;
    unsigned* myedges = edges + ((size_t)(set * 256 + cellid)) * RCAP;

    if (t == 0) {
      unsigned nN = 0;
      ncell[nN++] = (unsigned)cellid;               // CENTER FIRST (local id)
      for (int dy = -1; dy <= 1; ++dy)
        for (int dx = -1; dx <= 1; ++dx) {
          if (dx == 0 && dy == 0) continue;
          const int nx = cx + dx, ny = cy + dy;
          if (nx >= 0 && nx < 16 && ny >= 0 && ny < 16)
            ncell[nN++] = (unsigned)(ny * 16 + nx);
        }
      nN_sh = nN; nR_sh = nN * 16; eC = 0u; bad = 0u;
    }
    __syncthreads();
    const unsigned nR = nR_sh;

    // load packed {off,cnt} for nN cells x 16 parts of this set
    if (t < (int)nR) {
      const unsigned n = (unsigned)t >> 4, pp = (unsigned)t & 15u;
      const unsigned gpart = (unsigned)set * 16u + pp;
      const unsigned packed = partOfs[gpart * 256u + ncell[n]];
      U.p.runBase[t]  = (gpart << 9) + (packed & 0xFFFFu);
      U.p.runStart[t] = packed >> 16;               // count (prefixed below)
    }
    __syncthreads();
    if (t == 0) {
      unsigned acc = 0, na = 0;
      for (unsigned i = 0; i < nR; ++i) {
        const unsigned c = U.p.runStart[i];
        U.p.runStart[i] = acc;
        acc += c;
        if (i == 15) na = acc;                      // center = first 16 runs
      }
      na_sh = na; nb_sh = acc;
      if (acc > BCAP) bad = 1u;
    }
    __syncthreads();

    const unsigned na = na_sh, nb = nb_sh;
    const bool ok = (bad == 0u);                    // block-uniform

    if (ok) {
      // gather neighborhood entries via binary search over run starts
      for (unsigned idx = t; idx < nb; idx += 512) {
        unsigned lo = 0, hi = nR - 1;
        while (lo < hi) {
          const unsigned mid = (lo + hi + 1) >> 1;
          if (U.p.runStart[mid] <= idx) lo = mid; else hi = mid - 1;
        }
        const unsigned g = U.p.runBase[lo] + (idx - U.p.runStart[lo]);
        const float4 bx = partBox[g];               // plain: cross-dispatch
        U.p.B4[idx]  = bx;
        U.p.Bar[idx] = fmaxf(bx.z - bx.x, 0.0f) * fmaxf(bx.w - bx.y, 0.0f);
        U.p.Bid[idx] = partId[g];
      }
    }
    __syncthreads();

    if (ok) {
      // flattened pair phase: a = center entries [0,na), b = all [0,nb)
      const unsigned tot = na * nb;
      for (unsigned pi = t; pi < tot; pi += 512) {
        const unsigned ai = pi / nb, x = pi - ai * nb;
        const unsigned ia = U.p.Bid[ai], ib = U.p.Bid[x];
        if (ia < ib) {                              // emit-once; skips self
          const float4 A = U.p.B4[ai], B = U.p.B4[x];
          const float ix1 = fmaxf(A.x, B.x), iy1 = fmaxf(A.y, B.y);
          const float ix2 = fminf(A.z, B.z), iy2 = fminf(A.w, B.w);
          const float inter = fmaxf(ix2 - ix1, 0.0f) * fmaxf(iy2 - iy1, 0.0f);
          if (inter > 0.0f) {
            const float uni = U.p.Bar[ai] + U.p.Bar[x] - inter; // ref order
            const float iou = inter / fmaxf(uni, 1e-9f);        // ref expr
            if (iou > IOU_T) {
              const unsigned slot = atomicAdd(&eC, 1u);         // LDS atomic
              if (slot < RCAP) astore(&myedges[slot], (ia << 13) | ib);
            }
          }
        }
      }
    } else {
      // exact fallback (never taken for this data): a = rows in this cell,
      // b = ALL rows; out-of-neighborhood pairs have inter==0 geometrically,
      // so semantics are identical to the fast path.
      const float* src  = (set == 0) ? det : rpn;
      const int    strd = (set == 0) ? 9 : 6;
      for (int ra = 0; ra < NROWS; ++ra) {
        const float* pa = src + (size_t)ra * strd + 1;
        const float ax1 = pa[0], ay1 = pa[1], ax2 = pa[2], ay2 = pa[3];
        const float cxe = 0.5f * (ax1 + ax2), cye = 0.5f * (ay1 + ay2);
        const int ccx = min(15, max(0, (int)(cxe * (1.0f / 128.0f))));
        const int ccy = min(15, max(0, (int)(cye * (1.0f / 128.0f))));
        if (ccx != cx || ccy != cy) continue;       // uniform skip
        const float aar = fmaxf(ax2 - ax1, 0.0f) * fmaxf(ay2 - ay1, 0.0f);
        for (int rb = t; rb < NROWS; rb += 512) {
          if ((unsigned)ra >= (unsigned)rb) continue;
          const float* pb = src + (size_t)rb * strd + 1;
          const float bx1 = pb[0], by1 = pb[1], bx2 = pb[2], by2 = pb[3];
          const float ix1 = fmaxf(ax1, bx1), iy1 = fmaxf(ay1, by1);
          const float ix2 = fminf(ax2, bx2), iy2 = fminf(ay2, by2);
          const float inter = fmaxf(ix2 - ix1, 0.0f) * fmaxf(iy2 - iy1, 0.0f);
          if (inter > 0.0f) {
            const float bar = fmaxf(bx2 - bx1, 0.0f) * fmaxf(by2 - by1, 0.0f);
            const float uni = aar + bar - inter;
            const float iou = inter / fmaxf(uni, 1e-9f);
            if (iou > IOU_T) {
              const unsigned slot = atomicAdd(&eC, 1u);
              if (slot < RCAP) astore(&myedges[slot], ((unsigned)ra << 13) | (unsigned)rb);
            }
          }
        }
      }
    }
    __syncthreads();
    if (t == 0) astore(&ecnt[set * 256 + cellid], min(eC, RCAP));
  }

  // ---- ticket: last 32 arrivals become solver blocks ----------------------
  if (t == 0) {
    tk_sh = __hip_atomic_fetch_add(ticket, 1u, __ATOMIC_RELEASE,
                                   __HIP_MEMORY_SCOPE_AGENT);
  }
  __syncthreads();
  const unsigned tk = tk_sh;
  if (tk < 480u) return;                       // 480 blocks done; 32 solve

  if (t == 0) {
    while (aload(ticket) < 512u) __builtin_amdgcn_s_sleep(2);
    (void)__hip_atomic_load(ticket, __ATOMIC_ACQUIRE, __HIP_MEMORY_SCOPE_AGENT);
  }
  __syncthreads();

  // ---- solve + epilogue: sid in [0,32) ------------------------------------
  const unsigned sid = tk - 480u;
  const int set = (int)(sid >> 4);
  const int slice = (int)(sid & 15u);
  unsigned* gedges = edges + (size_t)set * 256 * RCAP;

  if (t < 256) U.s.rcnt[t] = min(aload(&ecnt[set * 256 + t]), RCAP);
  __syncthreads();

  // wave0 shuffle-scan of 256 region counts (4/lane)
  if (t < 64) {
    const unsigned h0 = U.s.rcnt[4 * t], h1 = U.s.rcnt[4 * t + 1];
    const unsigned h2 = U.s.rcnt[4 * t + 2], h3 = U.s.rcnt[4 * t + 3];
    const unsigned lsum = h0 + h1 + h2 + h3;
    unsigned incl = lsum;
    #pragma unroll
    for (int d = 1; d < 64; d <<= 1) {
      const unsigned v = __shfl_up(incl, d);
      if (t >= d) incl += v;
    }
    const unsigned base = incl - lsum;
    U.s.roff[4 * t] = base;               U.s.roff[4 * t + 1] = base + h0;
    U.s.roff[4 * t + 2] = base + h0 + h1; U.s.roff[4 * t + 3] = base + h0 + h1 + h2;
    if (t == 63) Etot_sh = incl;
  }
  if (t < NKW) U.s.kbuf[0][t] = 0xFFFFFFFFu;
  __syncthreads();

  const unsigned Etot = Etot_sh;
  const bool cached = (Etot <= ELDS);
  if (cached) {                 // gather: 2 threads per region (~6 loads ea)
    const unsigned rg = (unsigned)t >> 1, ln = (unsigned)t & 1u;
    const unsigned c = U.s.rcnt[rg], o = U.s.roff[rg];
    for (unsigned k = ln; k < c; k += 2u)
      U.s.eL[o + k] = aload(&gedges[(size_t)rg * RCAP + k]);
  }
  __syncthreads();

  int cur = 0;
  for (int round = 0; round < NROWS + 8; ++round) {
    const int nxt = cur ^ 1;
    if (t == 0) changed[round & 1] = 0;
    if (t < NKW) U.s.kbuf[nxt][t] = 0xFFFFFFFFu;
    __syncthreads();

    if (cached) {
      for (unsigned e = t; e < Etot; e += 512) {
        const unsigned pk = U.s.eL[e];
        const unsigned i = pk >> 13, j = pk & 8191u;
        if ((U.s.kbuf[cur][i >> 5] >> (i & 31)) & 1u)
          atomicAnd(&U.s.kbuf[nxt][j >> 5], ~(1u << (j & 31)));
      }
    } else {                    // exact slow path (never taken)
      for (unsigned r = (unsigned)t >> 1; r < 256u; r += 256u) {
        const unsigned c = U.s.rcnt[r];
        for (unsigned k = (unsigned)t & 1u; k < c; k += 2u) {
          const unsigned pk = aload(&gedges[(size_t)r * RCAP + k]);
          const unsigned i = pk >> 13, j = pk & 8191u;
          if ((U.s.kbuf[cur][i >> 5] >> (i & 31)) & 1u)
            atomicAnd(&U.s.kbuf[nxt][j >> 5], ~(1u << (j & 31)));
        }
      }
    }
    __syncthreads();

    if (t < NKW && U.s.kbuf[nxt][t] != U.s.kbuf[cur][t]) changed[round & 1] = 1;
    __syncthreads();

    cur = nxt;
    if (!changed[round & 1]) break;  // F(x)==x -> the unique fixpoint
  }

  // epilogue slice: 512 rows, coalesced float4 with magic-div row decode.
  const int r0 = slice * 512;
  if (set == 0) {
    {
      const int i = r0 + t;
      const bool kd = (U.s.kbuf[cur][i >> 5] >> (i & 31)) & 1u;
      const float* p = det + (size_t)i * 9;
      const float sc0 = p[5], sc1 = p[6], sc2 = p[7], sc3 = p[8];
      int am = 0; float best = sc0;
      if (sc1 > best) { best = sc1; am = 1; }   // first-max, like jnp.argmax
      if (sc2 > best) { best = sc2; am = 2; }
      if (sc3 > best) { best = sc3; am = 3; }
      U.s.vmsk[t] = (kd && am != 0) ? 1.0f : 0.0f;
      U.s.imsk[t] = (kd && am == 0) ? 1.0f : 0.0f;
    }
    __syncthreads();
    // slice = 512 rows x 9 dw = 4608 dw = 1152 float4, 16B-aligned bases
    const float4* in4 = reinterpret_cast<const float4*>(det + (size_t)r0 * 9);
    float4* o0 = reinterpret_cast<float4*>(out + (size_t)r0 * 9);
    float4* o1 = reinterpret_cast<float4*>(out + (size_t)NROWS * 9 + (size_t)r0 * 9);
    for (int q = t; q < 1152; q += 512) {
      const float4 v = in4[q];
      const float* vp = reinterpret_cast<const float*>(&v);
      float4 a, b;
      float* ap = reinterpret_cast<float*>(&a);
      float* bp = reinterpret_cast<float*>(&b);
      #pragma unroll
      for (int j = 0; j < 4; ++j) {
        const unsigned d = (unsigned)(q * 4 + j);
        const unsigned row = (d * 7282u) >> 16;        // == d/9 for d<4608
        ap[j] = vp[j] * U.s.vmsk[row];
        bp[j] = vp[j] * U.s.imsk[row];
      }
      o0[q] = a; o1[q] = b;
    }
  } else {
    {
      const int i = r0 + t;
      const bool kr = (U.s.kbuf[cur][i >> 5] >> (i & 31)) & 1u;
      U.s.vmsk[t] = kr ? 1.0f : 0.0f;
    }
    __syncthreads();
    // slice = 512 rows x 6 dw = 3072 dw = 768 float4, 16B-aligned bases
    const float4* in4 = reinterpret_cast<const float4*>(rpn + (size_t)r0 * 6);
    float4* o2 = reinterpret_cast<float4*>(out + (size_t)NROWS * 18 + (size_t)r0 * 6);
    for (int q = t; q < 768; q += 512) {
      const float4 v = in4[q];
      const float* vp = reinterpret_cast<const float*>(&v);
      float4 a;
      float* ap = reinterpret_cast<float*>(&a);
      #pragma unroll
      for (int j = 0; j < 4; ++j) {
        const unsigned d = (unsigned)(q * 4 + j);
        const unsigned row = (d * 10923u) >> 16;       // == d/6 for d<3072
        ap[j] = vp[j] * U.s.vmsk[row];
      }
      o2[q] = a;
    }
  }
}

// ---------------------------------------------------------------------------
extern "C" void kernel_launch(void* const* d_in, const int* in_sizes, int n_in,
                              void* d_out, int out_size, void* d_ws, size_t ws_size,
                              hipStream_t stream)
{
  const float* det = (const float*)d_in[0];   // 8192 x 9 fp32
  const float* rpn = (const float*)d_in[1];   // 8192 x 6 fp32
  float* out = (float*)d_out;                 // 8192*9 + 8192*9 + 8192*6 fp32

  char* ws = (char*)d_ws;
  unsigned* ecnt    = (unsigned*)(ws + OFF_ECNT);
  unsigned* ticket  = (unsigned*)(ws + OFF_TICK);
  unsigned* edges   = (unsigned*)(ws + OFF_EDGES);
  float4*   partBox = (float4*)  (ws + OFF_PBOX);
  unsigned* partId  = (unsigned*)(ws + OFF_PID);
  unsigned* partOfs = (unsigned*)(ws + OFF_POFS);

  bin_part_kernel<<<32, 512, 0, stream>>>(det, rpn, partBox, partId,
                                          partOfs, ticket);
  pairsolve_kernel<<<512, 512, 0, stream>>>(det, rpn, partBox, partId,
                                            partOfs, ecnt, edges, ticket, out);
}